// Round 8
// baseline (276.564 us; speedup 1.0000x reference)
//
#include <hip/hip_runtime.h>
#include <cstdint>
#include <cstddef>

typedef unsigned short u16;
typedef __attribute__((ext_vector_type(8))) short bf16x8;
typedef __attribute__((ext_vector_type(4))) float f32x4;

#define DEV static __device__ __forceinline__

DEV void gload_lds16(const void* g, void* l) {
  __builtin_amdgcn_global_load_lds((const __attribute__((address_space(1))) void*)g,
                                   (__attribute__((address_space(3))) void*)l, 16, 0, 0);
}

DEV u16 f2bf(float f) {  // RNE fp32 -> bf16 (finite inputs)
  unsigned x = __float_as_uint(f);
  return (u16)((x + 0x7FFFu + ((x >> 16) & 1u)) >> 16);
}

DEV unsigned cvtpk(float lo, float hi) {  // bf16(lo) in [15:0], bf16(hi) in [31:16]
  unsigned r;
  asm("v_cvt_pk_bf16_f32 %0, %1, %2" : "=v"(r) : "v"(lo), "v"(hi));
  return r;
}

#if __has_builtin(__builtin_amdgcn_exp2f)
DEV float fexp2(float x) { return __builtin_amdgcn_exp2f(x); }
#else
DEV float fexp2(float x) { return exp2f(x); }
#endif

// counted vmcnt wait + scheduling fence (rule #18)
#define WAITV(n)                                                   \
  do {                                                             \
    asm volatile("s_waitcnt vmcnt(" #n ")" ::: "memory");          \
    __builtin_amdgcn_sched_barrier(0);                             \
  } while (0)

DEV void sbar() {
  __builtin_amdgcn_sched_barrier(0);
  __builtin_amdgcn_s_barrier();
  __builtin_amdgcn_sched_barrier(0);
}

// ---------------- fp32 -> bf16 convert, 3 buffers in one launch ----------------
__global__ __launch_bounds__(256) void cvt3(const float* __restrict__ a, u16* __restrict__ da,
                                            const float* __restrict__ b, u16* __restrict__ db,
                                            const float* __restrict__ c, u16* __restrict__ dc) {
  int bid = blockIdx.x;
  const float* s;
  u16* d;
  int base;
  if (bid < 4096) { s = a; d = da; base = bid; }
  else if (bid < 7168) { s = b; d = db; base = bid - 4096; }
  else { s = c; d = dc; base = bid - 7168; }
  const int i = (base * 256 + (int)threadIdx.x) * 4;
  float4 v = *(const float4*)(s + i);
  uint2 p;
  p.x = (unsigned)f2bf(v.x) | ((unsigned)f2bf(v.y) << 16);
  p.y = (unsigned)f2bf(v.z) | ((unsigned)f2bf(v.w) << 16);
  *(uint2*)(d + i) = p;
}

// ---------------- GEMM: C = A * B^T (+bias) ----------------
// A[M][K] bf16 row-major, Bm[N][K] bf16 row-major.
// EPI 0: Cout = float[M][N], v + bias[e]
// EPI 1: QKV scatter: Q,K -> [which][b*16+h][s][d] bf16; V -> Vt[b*16+h][d][s] (transposed)
template <int EPI, int BM, int BN>
__global__ __launch_bounds__(256) void gemm_bt(const u16* __restrict__ A,
                                               const u16* __restrict__ Bm,
                                               const float* __restrict__ bias,
                                               void* __restrict__ Cout,
                                               u16* __restrict__ Vt,
                                               int M, int N, int K) {
  __shared__ u16 As[2][BM * 32];
  __shared__ u16 Bs[2][BN * 32];
  constexpr int MT = BM / 32, NT = BN / 32;
  const int cpx = (int)gridDim.x >> 3;
  const int bid = ((int)blockIdx.x & 7) * cpx + ((int)blockIdx.x >> 3);  // XCD chunking
  const int nb = N / BN;
  const int m0 = (bid / nb) * BM;
  const int n0 = (bid % nb) * BN;
  const int tid = threadIdx.x;
  const int w = tid >> 6, lane = tid & 63;
  const int wm = (w >> 1) * (BM / 2), wn = (w & 1) * (BN / 2);
  const int lr = lane & 15, lg = lane >> 4;

  f32x4 acc[MT][NT];
  const f32x4 z4 = {0.f, 0.f, 0.f, 0.f};
#pragma unroll
  for (int m = 0; m < MT; ++m)
#pragma unroll
    for (int n = 0; n < NT; ++n) acc[m][n] = z4;

  auto stage = [&](int ks, int buf) {
    const int k0 = ks << 5;
#pragma unroll
    for (int i = 0; i < BM * 4 / 256; ++i) {
      const int o = i * 256 + tid;
      const int row = o >> 2, c = o & 3;
      gload_lds16(A + (size_t)(m0 + row) * K + k0 + c * 8, &As[buf][(i * 256 + w * 64) * 8]);
    }
#pragma unroll
    for (int i = 0; i < BN * 4 / 256; ++i) {
      const int o = i * 256 + tid;
      const int row = o >> 2, c = o & 3;
      gload_lds16(Bm + (size_t)(n0 + row) * K + k0 + c * 8, &Bs[buf][(i * 256 + w * 64) * 8]);
    }
  };

  const int nk = K >> 5;
  stage(0, 0);
  __syncthreads();
  for (int ks = 0; ks < nk; ++ks) {
    const int cur = ks & 1;
    if (ks + 1 < nk) stage(ks + 1, cur ^ 1);
    bf16x8 af[MT], bfr[NT];
#pragma unroll
    for (int m = 0; m < MT; ++m)
      af[m] = *(const bf16x8*)&As[cur][(wm + m * 16 + lr) * 32 + lg * 8];
#pragma unroll
    for (int n = 0; n < NT; ++n)
      bfr[n] = *(const bf16x8*)&Bs[cur][(wn + n * 16 + lr) * 32 + lg * 8];
    __builtin_amdgcn_s_setprio(1);
#pragma unroll
    for (int m = 0; m < MT; ++m)
#pragma unroll
      for (int n = 0; n < NT; ++n)
        acc[m][n] = __builtin_amdgcn_mfma_f32_16x16x32_bf16(af[m], bfr[n], acc[m][n], 0, 0, 0);
    __builtin_amdgcn_s_setprio(0);
    __syncthreads();
  }

#pragma unroll
  for (int n = 0; n < NT; ++n) {
    const int e = n0 + wn + n * 16 + lr;
    const float bv = bias[e];
    if (EPI == 1 && (e >> 10) == 2) {
      // V: write transposed [bh][d][s], 4 consecutive s packed per store
      const int h = (e >> 6) & 15, d = e & 63;
#pragma unroll
      for (int m = 0; m < MT; ++m) {
        const int row0 = m0 + wm + m * 16 + lg * 4;
        const int bb = row0 >> 11, s0 = row0 & 2047;
        uint2 pv;
        pv.x = cvtpk(acc[m][n][0] + bv, acc[m][n][1] + bv);
        pv.y = cvtpk(acc[m][n][2] + bv, acc[m][n][3] + bv);
        *(uint2*)(Vt + (size_t)(bb * 16 + h) * 131072 + (size_t)d * 2048 + s0) = pv;
      }
    } else {
#pragma unroll
      for (int m = 0; m < MT; ++m) {
#pragma unroll
        for (int r = 0; r < 4; ++r) {
          const int row = m0 + wm + m * 16 + lg * 4 + r;  // D: col=lane&15, row=(lane>>4)*4+r
          const float v = acc[m][n][r] + bv;
          if (EPI == 0) {
            ((float*)Cout)[(size_t)row * N + e] = v;
          } else {
            const int which = e >> 10, h = (e >> 6) & 15, d = e & 63;
            const int bb = row >> 11, s = row & 2047;
            ((u16*)Cout)[(size_t)which * 4194304 +
                         (((size_t)(bb * 16 + h) * 2048 + s) << 6) + d] = f2bf(v);
          }
        }
      }
    }
  }
}

// ---------------- fused attention: q=128/block, LDS-staged, counted-vmcnt ----------------
// grid: 512 blocks (XCD-chunked) = bh(32) x qtile(16 of 128 q). 4 waves; each wave owns
// 16 q of half0 (srow0..+15) and 16 q of half1 (+64). K staged once serves BOTH halves
// (staging bytes, barriers, and K ds_reads per unit work all halved vs q=64 blocks).
// Pass 1: 128-t chunk ring (2x16KB), depth-1, WAITV(8), 16 barriers.
// Pass 2: 64-t K+V double-buffer, WAITV(12); NT weight stores never drained in-loop.
// Fixed-M0 softmax: p = exp2(s*log2e/8 - 8*log2e); masked -> 0.
// NOTE: no LDS-pointer arrays (hipcc "static initializer addrspacecast" error) --
// double-buffer pointers are computed arithmetically per iteration.
__global__ __launch_bounds__(256, 2) void attn(const u16* __restrict__ Q,
                                               const u16* __restrict__ Kg,
                                               const u16* __restrict__ Vtg,
                                               const int* __restrict__ mask,
                                               float* __restrict__ Wout,
                                               u16* __restrict__ Og) {
  __shared__ u16 SM[2][8192];      // 32KB: pass1 = 2x16KB chunk ring; pass2 = K dbuf | V dbuf
  __shared__ u16 Pl[4][2][1024];   // per wave x half: [16 q][64 t] bf16, XOR-swizzled
  const int L = ((int)blockIdx.x & 7) * 64 + ((int)blockIdx.x >> 3);  // XCD chunking
  const int bh = L >> 4, qt = L & 15;
  const int b = bh >> 4, h = bh & 15;
  const int tid = threadIdx.x;
  const int w = tid >> 6, lane = tid & 63;
  const int lr = lane & 15, lg = lane >> 4;
  const int srow0 = qt * 128 + w * 16;   // half0 rows; half1 = +64
  const float C2 = 0.18033688011112042f;  // log2(e)/8
  const float M2 = 11.541560327111707f;   // 8*log2(e)

  const u16* qr0 = Q + ((size_t)bh * 2048 + srow0 + lr) * 64;
  const u16* qr1 = qr0 + 64 * 64;
  const bf16x8 qf00 = *(const bf16x8*)(qr0 + lg * 8);
  const bf16x8 qf01 = *(const bf16x8*)(qr0 + 32 + lg * 8);
  const bf16x8 qf10 = *(const bf16x8*)(qr1 + lg * 8);
  const bf16x8 qf11 = *(const bf16x8*)(qr1 + 32 + lg * 8);
  const int* mrow = mask + b * 2048;

  auto stageChunk = [&](int ch, u16* dst) {  // 128 K rows (16KB), 4 gload_lds/thread
    const u16* g = Kg + (size_t)bh * 131072 + (size_t)ch * 8192;
#pragma unroll
    for (int iss = 0; iss < 4; ++iss) {
      const int o = iss * 256 + tid;
      const int row = o >> 3, c = o & 7;  // pre-swizzled source, linear LDS dest
      gload_lds16(g + row * 64 + ((c ^ (row & 7)) << 3), dst + (iss * 256 + w * 64) * 8);
    }
  };
  auto stageK = [&](int kt, u16* dst) {  // 64 K rows (8KB), 2 gload_lds/thread
    const u16* g = Kg + (size_t)bh * 131072 + (size_t)kt * 4096;
#pragma unroll
    for (int iss = 0; iss < 2; ++iss) {
      const int o = iss * 256 + tid;
      const int row = o >> 3, c = o & 7;
      gload_lds16(g + row * 64 + ((c ^ (row & 7)) << 3), dst + (iss * 256 + w * 64) * 8);
    }
  };
  auto stageV = [&](int kt, u16* dst) {  // 64 Vt rows (8KB), 2 gload_lds/thread
    const u16* g = Vtg + (size_t)bh * 131072 + kt * 64;  // [d][t] rows, stride 2048
#pragma unroll
    for (int iss = 0; iss < 2; ++iss) {
      const int o = iss * 256 + tid;
      const int row = o >> 3, c = o & 7;
      gload_lds16(g + (size_t)row * 2048 + ((c ^ (row & 7)) << 3),
                  dst + (iss * 256 + w * 64) * 8);
    }
  };
  // both-halves probs for one 64-t tile at LDS elem offset tt; kt = global tile index
  // pr[half][n][r]: q = srow0 + half*64 + lr, t = kt*64 + n*16 + lg*4 + r
  auto probsT = [&](const u16* kb, int tt, int kt, f32x4 pr[2][4]) {
    int4 mv[4];
#pragma unroll
    for (int n = 0; n < 4; ++n) mv[n] = *(const int4*)&mrow[kt * 64 + n * 16 + lg * 4];
    bf16x8 k0[4], k1[4];
#pragma unroll
    for (int n = 0; n < 4; ++n) {
      const int tr = n * 16 + lr;
      k0[n] = *(const bf16x8*)&kb[tt + tr * 64 + ((lg ^ (tr & 7)) << 3)];
      k1[n] = *(const bf16x8*)&kb[tt + tr * 64 + (((lg + 4) ^ (tr & 7)) << 3)];
    }
    f32x4 sc[2][4];
    __builtin_amdgcn_s_setprio(1);
#pragma unroll
    for (int n = 0; n < 4; ++n) {
      f32x4 s = {0.f, 0.f, 0.f, 0.f};
      s = __builtin_amdgcn_mfma_f32_16x16x32_bf16(k0[n], qf00, s, 0, 0, 0);
      s = __builtin_amdgcn_mfma_f32_16x16x32_bf16(k1[n], qf01, s, 0, 0, 0);
      sc[0][n] = s;
      f32x4 s2 = {0.f, 0.f, 0.f, 0.f};
      s2 = __builtin_amdgcn_mfma_f32_16x16x32_bf16(k0[n], qf10, s2, 0, 0, 0);
      s2 = __builtin_amdgcn_mfma_f32_16x16x32_bf16(k1[n], qf11, s2, 0, 0, 0);
      sc[1][n] = s2;
    }
    __builtin_amdgcn_s_setprio(0);
#pragma unroll
    for (int hh = 0; hh < 2; ++hh)
#pragma unroll
      for (int n = 0; n < 4; ++n) {
        f32x4 p;
        p[0] = (mv[n].x == 0) ? 0.f : fexp2(fmaf(sc[hh][n][0], C2, -M2));
        p[1] = (mv[n].y == 0) ? 0.f : fexp2(fmaf(sc[hh][n][1], C2, -M2));
        p[2] = (mv[n].z == 0) ? 0.f : fexp2(fmaf(sc[hh][n][2], C2, -M2));
        p[3] = (mv[n].w == 0) ? 0.f : fexp2(fmaf(sc[hh][n][3], C2, -M2));
        pr[hh][n] = p;
      }
  };

  // ---- pass 1: per-lane denominators; 128-t chunk ring, depth-1, 16 barriers ----
  float ls0 = 0.f, ls1 = 0.f;
  stageChunk(0, &SM[0][0]);
  WAITV(0);
  sbar();
  for (int r = 0; r < 16; ++r) {
    const u16* cb = &SM[r & 1][0];
    if (r + 1 < 16) stageChunk(r + 1, &SM[(r + 1) & 1][0]);
#pragma unroll
    for (int half = 0; half < 2; ++half) {
      f32x4 pr[2][4];
      probsT(cb, half * 4096, 2 * r + half, pr);
      {
        float s0 = (pr[0][0][0] + pr[0][0][1]) + (pr[0][0][2] + pr[0][0][3]);
        float s1 = (pr[0][1][0] + pr[0][1][1]) + (pr[0][1][2] + pr[0][1][3]);
        float s2 = (pr[0][2][0] + pr[0][2][1]) + (pr[0][2][2] + pr[0][2][3]);
        float s3 = (pr[0][3][0] + pr[0][3][1]) + (pr[0][3][2] + pr[0][3][3]);
        ls0 += (s0 + s1) + (s2 + s3);
      }
      {
        float s0 = (pr[1][0][0] + pr[1][0][1]) + (pr[1][0][2] + pr[1][0][3]);
        float s1 = (pr[1][1][0] + pr[1][1][1]) + (pr[1][1][2] + pr[1][1][3]);
        float s2 = (pr[1][2][0] + pr[1][2][1]) + (pr[1][2][2] + pr[1][2][3]);
        float s3 = (pr[1][3][0] + pr[1][3][1]) + (pr[1][3][2] + pr[1][3][3]);
        ls1 += (s0 + s1) + (s2 + s3);
      }
    }
    if (r + 1 < 16) {
      WAITV(8);  // stage(r+1) done; 2x mask4 may remain
      sbar();
    }
  }
  ls0 += __shfl_xor(ls0, 16);
  ls0 += __shfl_xor(ls0, 32);
  ls1 += __shfl_xor(ls1, 16);
  ls1 += __shfl_xor(ls1, 32);
  const float rl0 = 1.0f / ls0, rl1 = 1.0f / ls1;

  // ---- pass 2: weights + PV; K+V double-buffer, stores never drained ----
  sbar();  // all waves out of pass-1 SM reads
  f32x4 oacc[2][4];
  const f32x4 z4 = {0.f, 0.f, 0.f, 0.f};
#pragma unroll
  for (int hh = 0; hh < 2; ++hh)
#pragma unroll
    for (int n = 0; n < 4; ++n) oacc[hh][n] = z4;

  float* wrow0 = Wout + ((size_t)bh * 2048 + srow0 + lr) * 2048;
  float* wrow1 = wrow0 + (size_t)64 * 2048;
  char* plw0 = (char*)&Pl[w][0][0];
  char* plw1 = (char*)&Pl[w][1][0];
  const int pswz = (lr & 7) << 4;

  stageK(0, &SM[0][0]);
  stageV(0, &SM[1][0]);
  WAITV(0);
  sbar();
  for (int t = 0; t < 32; ++t) {
    const int cur = t & 1;
    u16* kcur = &SM[0][cur * 4096];
    u16* vcur = &SM[1][cur * 4096];
    if (t + 1 < 32) {
      stageK(t + 1, &SM[0][(cur ^ 1) * 4096]);
      stageV(t + 1, &SM[1][(cur ^ 1) * 4096]);
    }
    f32x4 pr[2][4];
    probsT(kcur, 0, t, pr);
#pragma unroll
    for (int n = 0; n < 4; ++n) {  // half 0 stores + P
      f32x4 wv;
      wv[0] = pr[0][n][0] * rl0;
      wv[1] = pr[0][n][1] * rl0;
      wv[2] = pr[0][n][2] * rl0;
      wv[3] = pr[0][n][3] * rl0;
      __builtin_nontemporal_store(wv, (f32x4*)&wrow0[t * 64 + n * 16 + lg * 4]);
      uint2 pw;
      pw.x = cvtpk(wv[0], wv[1]);
      pw.y = cvtpk(wv[2], wv[3]);
      *(uint2*)(plw0 + (lr * 128 + ((n * 32 + lg * 8) ^ pswz))) = pw;
    }
#pragma unroll
    for (int n = 0; n < 4; ++n) {  // half 1 stores + P
      f32x4 wv;
      wv[0] = pr[1][n][0] * rl1;
      wv[1] = pr[1][n][1] * rl1;
      wv[2] = pr[1][n][2] * rl1;
      wv[3] = pr[1][n][3] * rl1;
      __builtin_nontemporal_store(wv, (f32x4*)&wrow1[t * 64 + n * 16 + lg * 4]);
      uint2 pw;
      pw.x = cvtpk(wv[0], wv[1]);
      pw.y = cvtpk(wv[2], wv[3]);
      *(uint2*)(plw1 + (lr * 128 + ((n * 32 + lg * 8) ^ pswz))) = pw;
    }
    const bf16x8 pA0 = *(const bf16x8*)(plw0 + (lr * 128 + ((lg * 16) ^ pswz)));
    const bf16x8 pA1 = *(const bf16x8*)(plw0 + (lr * 128 + ((64 + lg * 16) ^ pswz)));
    const bf16x8 pB0 = *(const bf16x8*)(plw1 + (lr * 128 + ((lg * 16) ^ pswz)));
    const bf16x8 pB1 = *(const bf16x8*)(plw1 + (lr * 128 + ((64 + lg * 16) ^ pswz)));
    __builtin_amdgcn_s_setprio(1);
#pragma unroll
    for (int n = 0; n < 4; ++n) {  // V frags shared across halves
      const int dr = n * 16 + lr;
      const bf16x8 v0 = *(const bf16x8*)&vcur[dr * 64 + ((lg ^ (dr & 7)) << 3)];
      const bf16x8 v1 = *(const bf16x8*)&vcur[dr * 64 + (((lg + 4) ^ (dr & 7)) << 3)];
      oacc[0][n] = __builtin_amdgcn_mfma_f32_16x16x32_bf16(pA0, v0, oacc[0][n], 0, 0, 0);
      oacc[0][n] = __builtin_amdgcn_mfma_f32_16x16x32_bf16(pA1, v1, oacc[0][n], 0, 0, 0);
      oacc[1][n] = __builtin_amdgcn_mfma_f32_16x16x32_bf16(pB0, v0, oacc[1][n], 0, 0, 0);
      oacc[1][n] = __builtin_amdgcn_mfma_f32_16x16x32_bf16(pB1, v1, oacc[1][n], 0, 0, 0);
    }
    __builtin_amdgcn_s_setprio(0);
    if (t + 1 < 32) {
      WAITV(12);  // stage(t+1) done; mask4 + 8 NT stores may remain
      sbar();
    }
  }

  // O: lane holds O[q = srow0 + half*64 + lg*4 + r][d = n*16 + lr]
#pragma unroll
  for (int hh = 0; hh < 2; ++hh)
#pragma unroll
    for (int n = 0; n < 4; ++n)
#pragma unroll
      for (int r = 0; r < 4; ++r) {
        const int s = srow0 + hh * 64 + lg * 4 + r;
        Og[((size_t)(b * 2048 + s)) * 1024 + h * 64 + n * 16 + lr] = f2bf(oacc[hh][n][r]);
      }
}

// ---------------- launch ----------------
extern "C" void kernel_launch(void* const* d_in, const int* in_sizes, int n_in,
                              void* d_out, int out_size, void* d_ws, size_t ws_size,
                              hipStream_t stream) {
  const float* x     = (const float*)d_in[0];
  const int*   mask  = (const int*)d_in[1];
  const float* qkv_w = (const float*)d_in[2];
  const float* qkv_b = (const float*)d_in[3];
  const float* wo_w  = (const float*)d_in[4];
  const float* wo_b  = (const float*)d_in[5];
  float* out = (float*)d_out;

  char* ws = (char*)d_ws;
  u16* xb   = (u16*)(ws);                          // 4096x1024
  u16* qwb  = (u16*)(ws + (8u << 20));             // 3072x1024
  u16* wob  = (u16*)(ws + (14u << 20));            // 1024x1024
  u16* qkvb = (u16*)(ws + (16u << 20));            // Q,K: [bh][s][64] bf16 (V slot unused)
  u16* vt   = (u16*)(ws + (40u << 20));            // [bh][64][2048] bf16 (written by QKV epi)
  u16* ob   = (u16*)(ws + (48u << 20));            // attn out [4096][1024] bf16

  cvt3<<<8192, 256, 0, stream>>>(x, xb, qkv_w, qwb, wo_w, wob);
  gemm_bt<1, 128, 128><<<768, 256, 0, stream>>>(xb, qwb, qkv_b, qkvb, vt, 4096, 3072, 1024);
  attn<<<512, 256, 0, stream>>>(qkvb, qkvb + 4194304, vt, mask, out + 4194304, ob);
  gemm_bt<0, 128, 64><<<512, 256, 0, stream>>>(ob, wob, wo_b, out, nullptr, 4096, 1024, 1024);
}